// Round 1
// baseline (1188.746 us; speedup 1.0000x reference)
//
#include <hip/hip_runtime.h>
#include <cstddef>

#define T_LEN 512
#define S_DIM 8
#define O_DIM 4

typedef _Float16 f16x8 __attribute__((ext_vector_type(8)));
typedef float    f32x4 __attribute__((ext_vector_type(4)));

#define MFMA16(a, b, c) __builtin_amdgcn_mfma_f32_16x16x32_f16((a), (b), (c), 0, 0, 0)

__device__ __forceinline__ float sigm_f(float x) {
    return 1.0f / (1.0f + __expf(-x));
}
__device__ __forceinline__ float tanh_f(float x) {
    x = fminf(30.0f, fmaxf(-30.0f, x));
    float e = __expf(-2.0f * x);
    return (1.0f - e) / (1.0f + e);
}

// B-fragment for 16x16x32 f16 MFMA from a row-major [K x 64] fp32 matrix.
// Lane holds B[k][n] with n given (absolute col), k = k0 + (lane>>4)*8 + j.
__device__ __forceinline__ f16x8 load_bt(const float* __restrict__ W, int k0, int n) {
    const int lane = threadIdx.x & 63;
    const float* p = W + (size_t)(k0 + ((lane >> 4) << 3)) * 64 + n;
    f16x8 r;
#pragma unroll
    for (int j = 0; j < 8; ++j) r[j] = (_Float16)p[(size_t)j * 64];
    return r;
}

// A-fragment from LDS state array [16][72] (pad 72 breaks the 16-way bank aliasing).
// Lane holds A[m][k]: m = lane&15, k = kt*32 + (lane>>4)*8 + j (j=0..7 contiguous).
__device__ __forceinline__ f16x8 ld_af(const _Float16* base, int kt) {
    const int lane = threadIdx.x & 63;
    const int m = lane & 15, q = lane >> 4;
    return *(const f16x8*)(base + m * 72 + kt * 32 + q * 8);
}

__global__ __launch_bounds__(256, 1) void ANIMAZeroExact_86887188398421_kernel(
    const float* __restrict__ x,
    const float* __restrict__ Wenc_w, const float* __restrict__ Wenc_b,
    const float* __restrict__ WfW, const float* __restrict__ WfI, const float* __restrict__ WfA,
    const float* __restrict__ Wg_w, const float* __restrict__ Wg_b,
    const float* __restrict__ Iz_w, const float* __restrict__ Iz_b,
    const float* __restrict__ Ir_w, const float* __restrict__ Ir_b,
    const float* __restrict__ Ih_w, const float* __restrict__ Ih_b,
    const float* __restrict__ AfW, const float* __restrict__ AfI, const float* __restrict__ AfA,
    const float* __restrict__ Ag_w, const float* __restrict__ Ag_b,
    const float* __restrict__ phi_w, const float* __restrict__ phi_b,
    float* __restrict__ out)
{
    __shared__ _Float16 Wl[16][72];   // W state (f16)
    __shared__ _Float16 Il[16][72];   // I state
    __shared__ _Float16 Al[16][72];   // A state
    __shared__ _Float16 Rl[16][72];   // r*I scratch

    const int tid  = threadIdx.x;
    const int lane = tid & 63;
    const int w    = tid >> 6;        // wave id 0..3: owns output cols [16w, 16w+16)
    const int q    = lane >> 4;       // quad
    const int c    = lane & 15;
    const int nb   = w * 16;
    const int n    = nb + c;          // this lane's output column
    const int r0   = blockIdx.x * 16; // this block's 16 batch rows

    // ---- zero initial states ----
    for (int i = tid; i < 16 * 72; i += 256) {
        ((_Float16*)Wl)[i] = (_Float16)0.0f;
        ((_Float16*)Il)[i] = (_Float16)0.0f;
        ((_Float16*)Al)[i] = (_Float16)0.0f;
        ((_Float16*)Rl)[i] = (_Float16)0.0f;
    }

    // ---- preload ALL weight B-fragments into registers (one time) ----
    f16x8 S1B[6], G1B[4], ZB[6], RB[6], HB[6], AB[6], AGB[4], phiB[2], encB;
#pragma unroll
    for (int j = 0; j < 2; ++j) {
        S1B[j]     = load_bt(WfW, 32 * j, n);
        S1B[2 + j] = load_bt(WfI, 32 * j, n);
        S1B[4 + j] = load_bt(WfA, 32 * j, n);
        AB[j]      = load_bt(AfW, 32 * j, n);
        AB[2 + j]  = load_bt(AfI, 32 * j, n);
        AB[4 + j]  = load_bt(AfA, 32 * j, n);
    }
#pragma unroll
    for (int j = 0; j < 4; ++j) {
        G1B[j] = load_bt(Wg_w, 32 * j, n);
        AGB[j] = load_bt(Ag_w, 32 * j, n);
    }
#pragma unroll
    for (int j = 0; j < 6; ++j) {
        ZB[j] = load_bt(Iz_w, 32 * j, n);
        RB[j] = load_bt(Ir_w, 32 * j, n);
        HB[j] = load_bt(Ih_w, 32 * j, n);
    }
    // encoder B-frag: [8 x 64] padded to K=32 (only quad 0 holds real k=0..7)
#pragma unroll
    for (int j = 0; j < 8; ++j)
        encB[j] = (q == 0) ? (_Float16)Wenc_w[j * 64 + n] : (_Float16)0.0f;
    // phi B-frag: [64 x 4] padded to N=16 (cols >= 4 zero); tile cols are 0..15 -> use c
#pragma unroll
    for (int kt = 0; kt < 2; ++kt) {
#pragma unroll
        for (int j = 0; j < 8; ++j) {
            int k = kt * 32 + q * 8 + j;
            phiB[kt][j] = (c < O_DIM) ? (_Float16)phi_w[k * O_DIM + c] : (_Float16)0.0f;
        }
    }

    // biases for this lane's column
    const float bias_g  = Wg_b[n];
    const float bias_z  = Iz_b[n];
    const float bias_r  = Ir_b[n];
    const float bias_h  = Ih_b[n];
    const float bias_ag = Ag_b[n];
    const float bias_e  = Wenc_b[n];
    const float bias_p  = (c < O_DIM) ? phi_b[c] : 0.0f;

    // x prefetch (row m = c of this block); quads 1..3 load redundantly (L1 hit)
    const float* xp = x + (size_t)(r0 + c) * (T_LEN * S_DIM);
    float xv[8];
    {
        const float4 a = *(const float4*)(xp);
        const float4 b = *(const float4*)(xp + 4);
        xv[0] = a.x; xv[1] = a.y; xv[2] = a.z; xv[3] = a.w;
        xv[4] = b.x; xv[5] = b.y; xv[6] = b.z; xv[7] = b.w;
    }

    f32x4 zero4 = {0.0f, 0.0f, 0.0f, 0.0f};

    __syncthreads();   // states zeroed

    for (int t = 0; t < T_LEN; ++t) {
        // x A-fragment for this step (only quad 0 carries k=0..7)
        f16x8 xf;
#pragma unroll
        for (int j = 0; j < 8; ++j)
            xf[j] = (q == 0) ? (_Float16)xv[j] : (_Float16)0.0f;

        // R1: read old-state A-fragments (kept in regs for the whole step)
        f16x8 aW0 = ld_af(&Wl[0][0], 0), aW1 = ld_af(&Wl[0][0], 1);
        f16x8 aI0 = ld_af(&Il[0][0], 0), aI1 = ld_af(&Il[0][0], 1);
        f16x8 aA0 = ld_af(&Al[0][0], 0), aA1 = ld_af(&Al[0][0], 1);
        __syncthreads();   // (A) all old-state reads done before W_new overwrite

        // prefetch next step's x (latency hidden across stages)
        {
            int tn = (t + 1 < T_LEN) ? t + 1 : t;
            const float4 a = *(const float4*)(xp + (size_t)tn * S_DIM);
            const float4 b = *(const float4*)(xp + (size_t)tn * S_DIM + 4);
            xv[0] = a.x; xv[1] = a.y; xv[2] = a.z; xv[3] = a.w;
            xv[4] = b.x; xv[5] = b.y; xv[6] = b.z; xv[7] = b.w;
        }

        // ---- stage 1: xt, W_in, Wg -> W_new ----
        f32x4 enc = MFMA16(xf, encB, zero4);
        f32x4 p1a = MFMA16(aW0, S1B[0], zero4);
        f32x4 p1b = MFMA16(aW1, S1B[1], zero4);
        p1a = MFMA16(aI0, S1B[2], p1a);
        p1b = MFMA16(aI1, S1B[3], p1b);
        p1a = MFMA16(aA0, S1B[4], p1a);
        p1b = MFMA16(aA1, S1B[5], p1b);
        f32x4 g1a = MFMA16(aI0, G1B[0], zero4);
        f32x4 g1b = MFMA16(aI1, G1B[1], zero4);
        g1a = MFMA16(aA0, G1B[2], g1a);
        g1b = MFMA16(aA1, G1B[3], g1b);
#pragma unroll
        for (int i = 0; i < 4; ++i) {
            float xt  = tanh_f(enc[i] + bias_e);
            float win = xt + p1a[i] + p1b[i];
            float wg  = sigm_f(g1a[i] + g1b[i] + bias_g);
            Wl[4 * q + i][n] = (_Float16)(tanh_f(win) * wg);
        }
        __syncthreads();   // (B) W_new staged

        // ---- stage 2: z, r; stage r*I ----
        f16x8 aN0 = ld_af(&Wl[0][0], 0), aN1 = ld_af(&Wl[0][0], 1);
        f32x4 za = MFMA16(aN0, ZB[0], zero4);
        f32x4 zc = MFMA16(aN1, ZB[1], zero4);
        za = MFMA16(aI0, ZB[2], za);
        zc = MFMA16(aI1, ZB[3], zc);
        za = MFMA16(aA0, ZB[4], za);
        zc = MFMA16(aA1, ZB[5], zc);
        f32x4 ra = MFMA16(aN0, RB[0], zero4);
        f32x4 rc = MFMA16(aN1, RB[1], zero4);
        ra = MFMA16(aI0, RB[2], ra);
        rc = MFMA16(aI1, RB[3], rc);
        ra = MFMA16(aA0, RB[4], ra);
        rc = MFMA16(aA1, RB[5], rc);
        float zv[4], Iv[4];
#pragma unroll
        for (int i = 0; i < 4; ++i) {
            zv[i] = sigm_f(za[i] + zc[i] + bias_z);
            float rv = sigm_f(ra[i] + rc[i] + bias_r);
            Iv[i] = (float)Il[4 * q + i][n];
            Rl[4 * q + i][n] = (_Float16)(rv * Iv[i]);
        }
        __syncthreads();   // (C) r*I staged

        // ---- stage 3: h -> I_new ----
        f16x8 aR0 = ld_af(&Rl[0][0], 0), aR1 = ld_af(&Rl[0][0], 1);
        f32x4 ha = MFMA16(aN0, HB[0], zero4);
        f32x4 hc = MFMA16(aN1, HB[1], zero4);
        ha = MFMA16(aR0, HB[2], ha);
        hc = MFMA16(aR1, HB[3], hc);
        ha = MFMA16(aA0, HB[4], ha);
        hc = MFMA16(aA1, HB[5], hc);
#pragma unroll
        for (int i = 0; i < 4; ++i) {
            float hv = tanh_f(ha[i] + hc[i] + bias_h);
            float In = (1.0f - zv[i]) * Iv[i] + zv[i] * hv;
            Il[4 * q + i][n] = (_Float16)In;
        }
        __syncthreads();   // (D) I_new staged

        // ---- stage 4: A_in, Ag -> A_new ----
        f16x8 aJ0 = ld_af(&Il[0][0], 0), aJ1 = ld_af(&Il[0][0], 1);
        f32x4 pa = MFMA16(aN0, AB[0], zero4);
        f32x4 pc = MFMA16(aN1, AB[1], zero4);
        pa = MFMA16(aJ0, AB[2], pa);
        pc = MFMA16(aJ1, AB[3], pc);
        pa = MFMA16(aA0, AB[4], pa);
        pc = MFMA16(aA1, AB[5], pc);
        f32x4 ga = MFMA16(aN0, AGB[0], zero4);
        f32x4 gc = MFMA16(aN1, AGB[1], zero4);
        ga = MFMA16(aJ0, AGB[2], ga);
        gc = MFMA16(aJ1, AGB[3], gc);
#pragma unroll
        for (int i = 0; i < 4; ++i) {
            float av = tanh_f(pa[i] + pc[i]) * sigm_f(ga[i] + gc[i] + bias_ag);
            Al[4 * q + i][n] = (_Float16)av;
        }
        __syncthreads();   // (E) A_new staged

        // ---- stage 5: action = A_new @ phi + b; store (wave 0 only) ----
        f16x8 aP0 = ld_af(&Al[0][0], 0), aP1 = ld_af(&Al[0][0], 1);
        f32x4 act = MFMA16(aP0, phiB[0], zero4);
        act = MFMA16(aP1, phiB[1], act);
        if (w == 0 && c < O_DIM) {
#pragma unroll
            for (int i = 0; i < 4; ++i)
                out[(size_t)(r0 + 4 * q + i) * (T_LEN * O_DIM) + t * O_DIM + c] = act[i] + bias_p;
        }
    }
}

extern "C" void kernel_launch(void* const* d_in, const int* in_sizes, int n_in,
                              void* d_out, int out_size, void* d_ws, size_t ws_size,
                              hipStream_t stream) {
    ANIMAZeroExact_86887188398421_kernel<<<dim3(64), dim3(256), 0, stream>>>(
        (const float*)d_in[0],                          // x
        (const float*)d_in[1],  (const float*)d_in[2],  // W_enc_w, W_enc_b
        (const float*)d_in[3],  (const float*)d_in[4],  (const float*)d_in[5],   // W_from_W/I/A
        (const float*)d_in[6],  (const float*)d_in[7],  // W_gate_w, W_gate_b
        (const float*)d_in[8],  (const float*)d_in[9],  // I_z_w, I_z_b
        (const float*)d_in[10], (const float*)d_in[11], // I_r_w, I_r_b
        (const float*)d_in[12], (const float*)d_in[13], // I_h_w, I_h_b
        (const float*)d_in[14], (const float*)d_in[15], (const float*)d_in[16],  // A_from_W/I/A
        (const float*)d_in[17], (const float*)d_in[18], // A_gate_w, A_gate_b
        (const float*)d_in[19], (const float*)d_in[20], // phi_w, phi_b
        (float*)d_out);
}

// Round 2
// 806.968 us; speedup vs baseline: 1.4731x; 1.4731x over previous
//
#include <hip/hip_runtime.h>
#include <cstddef>
#include <cstdint>

#define T_LEN 512
#define O_DIM 4

typedef _Float16 f16x8 __attribute__((ext_vector_type(8)));
typedef float    f32x4 __attribute__((ext_vector_type(4)));

#define MFMA(a, b, c) __builtin_amdgcn_mfma_f32_16x16x32_f16((a), (b), (c), 0, 0, 0)

__device__ __forceinline__ float sigm_f(float x) {
    // rcp(1 + 2^(-x*log2e)) : 4 VALU, saturates cleanly (rcp(inf)=0)
    return __builtin_amdgcn_rcpf(1.0f + __builtin_amdgcn_exp2f(x * -1.44269504f));
}
__device__ __forceinline__ float tanh_f(float x) {
    // 1 - 2/(2^(2x*log2e)+1) : 5 VALU, exact at +/-inf, no NaN for finite x
    float e = __builtin_amdgcn_exp2f(x * 2.88539008f);
    return __builtin_fmaf(-2.0f, __builtin_amdgcn_rcpf(e + 1.0f), 1.0f);
}

__device__ __forceinline__ f16x8 zf8() {
    f16x8 r;
#pragma unroll
    for (int j = 0; j < 8; ++j) r[j] = (_Float16)0.0f;
    return r;
}

// B-fragment for 16x16x32 f16 MFMA from a row-major [K x 64] fp32 matrix.
__device__ __forceinline__ f16x8 load_bt(const float* __restrict__ W, int k0, int n) {
    const int lane = threadIdx.x & 63;
    const float* p = W + (size_t)(k0 + ((lane >> 4) << 3)) * 64 + n;
    f16x8 r;
#pragma unroll
    for (int j = 0; j < 8; ++j) r[j] = (_Float16)p[(size_t)j * 64];
    return r;
}

// A-fragment from LDS state array [16][72] f16 (pad 72 -> conflict-optimal b128).
__device__ __forceinline__ f16x8 ld_af(const _Float16* base, int kt) {
    const int lane = threadIdx.x & 63;
    const int m = lane & 15, q = lane >> 4;
    return *(const f16x8*)(base + m * 72 + kt * 32 + q * 8);
}

__global__ __launch_bounds__(256, 1) void ANIMAZeroExact_86887188398421_kernel(
    const float* __restrict__ x,
    const float* __restrict__ Wenc_w, const float* __restrict__ Wenc_b,
    const float* __restrict__ WfW, const float* __restrict__ WfI, const float* __restrict__ WfA,
    const float* __restrict__ Wg_w, const float* __restrict__ Wg_b,
    const float* __restrict__ Iz_w, const float* __restrict__ Iz_b,
    const float* __restrict__ Ir_w, const float* __restrict__ Ir_b,
    const float* __restrict__ Ih_w, const float* __restrict__ Ih_b,
    const float* __restrict__ AfW, const float* __restrict__ AfI, const float* __restrict__ AfA,
    const float* __restrict__ Ag_w, const float* __restrict__ Ag_b,
    const float* __restrict__ phi_w, const float* __restrict__ phi_b,
    float* __restrict__ out)
{
    __shared__ __align__(16) _Float16 Wl[16][72];
    __shared__ __align__(16) _Float16 Il[16][72];
    __shared__ __align__(16) _Float16 Al[16][72];
    __shared__ __align__(16) _Float16 Rl[16][72];
    __shared__ __align__(16) float xtile[16 * 132];  // [row][u*8] (132-dword row stride: 2-way banks on reads)
    __shared__ __align__(16) float actb[16 * 64];    // [row][slot][o]

    const int tid  = threadIdx.x;
    const int lane = tid & 63;
    const int w    = tid >> 6;
    const int q    = lane >> 4;
    const int c    = lane & 15;
    const int n    = w * 16 + c;
    const int r0   = blockIdx.x * 16;
    const int xr   = tid >> 4, xu = tid & 15;       // flush/x-stage mapping

    // zero states
    for (int i = tid; i < 16 * 72; i += 256) {
        ((_Float16*)Wl)[i] = (_Float16)0.0f;
        ((_Float16*)Il)[i] = (_Float16)0.0f;
        ((_Float16*)Al)[i] = (_Float16)0.0f;
        ((_Float16*)Rl)[i] = (_Float16)0.0f;
    }

    // ---- weight B-fragments, resident in registers for the whole kernel ----
    f16x8 S1B[6], G1B[4], ZB[6], RB[6], HB[6], AB[6], AGB[4], phiB[2], encB;
#pragma unroll
    for (int j = 0; j < 2; ++j) {
        S1B[j] = load_bt(WfW, 32 * j, n);  S1B[2 + j] = load_bt(WfI, 32 * j, n);  S1B[4 + j] = load_bt(WfA, 32 * j, n);
        AB[j]  = load_bt(AfW, 32 * j, n);  AB[2 + j]  = load_bt(AfI, 32 * j, n);  AB[4 + j]  = load_bt(AfA, 32 * j, n);
    }
#pragma unroll
    for (int j = 0; j < 4; ++j) { G1B[j] = load_bt(Wg_w, 32 * j, n); AGB[j] = load_bt(Ag_w, 32 * j, n); }
#pragma unroll
    for (int j = 0; j < 6; ++j) { ZB[j] = load_bt(Iz_w, 32 * j, n); RB[j] = load_bt(Ir_w, 32 * j, n); HB[j] = load_bt(Ih_w, 32 * j, n); }
#pragma unroll
    for (int j = 0; j < 8; ++j) encB[j] = (q == 0) ? (_Float16)Wenc_w[j * 64 + n] : (_Float16)0.0f;
#pragma unroll
    for (int kt = 0; kt < 2; ++kt)
#pragma unroll
        for (int j = 0; j < 8; ++j) {
            int k = kt * 32 + q * 8 + j;
            phiB[kt][j] = (c < O_DIM && w == 0) ? (_Float16)phi_w[k * O_DIM + c] : (_Float16)0.0f;
        }

    const float bias_g  = Wg_b[n],  bias_z = Iz_b[n], bias_r = Ir_b[n];
    const float bias_h  = Ih_b[n],  bias_ag = Ag_b[n], bias_e = Wenc_b[n];
    const float bias_p  = (c < O_DIM) ? phi_b[c] : 0.0f;

    const float* xgr = x + (size_t)(r0 + xr) * (T_LEN * 8);

    // ---- prologue: stage x-tile for steps 1..16; compute xt(0) directly ----
    {
        int off = 8 + xu * 8;  // t0=1
        if (off > T_LEN * 8 - 8) off = T_LEN * 8 - 8;
        float4 a = *(const float4*)(xgr + off);
        float4 b = *(const float4*)(xgr + off + 4);
        float* d = &xtile[xr * 132 + xu * 8];
        *(float4*)d = a; *(float4*)(d + 4) = b;
    }
    float xt[4];
    {
        const float* xrow = x + (size_t)(r0 + c) * (T_LEN * 8);
        float4 a = *(const float4*)(xrow);
        float4 b = *(const float4*)(xrow + 4);
        f16x8 xf;
        float m = (q == 0) ? 1.0f : 0.0f;
        xf[0] = (_Float16)(a.x * m); xf[1] = (_Float16)(a.y * m); xf[2] = (_Float16)(a.z * m); xf[3] = (_Float16)(a.w * m);
        xf[4] = (_Float16)(b.x * m); xf[5] = (_Float16)(b.y * m); xf[6] = (_Float16)(b.z * m); xf[7] = (_Float16)(b.w * m);
        f32x4 zero4 = {0.f, 0.f, 0.f, 0.f};
        f32x4 e0 = MFMA(xf, encB, zero4);
#pragma unroll
        for (int i = 0; i < 4; ++i) xt[i] = tanh_f(e0[i] + bias_e);
    }

    f16x8 sW0 = zf8(), sW1 = zf8(), sI0 = zf8(), sI1 = zf8();
    f32x4 zero4 = {0.f, 0.f, 0.f, 0.f};

    __syncthreads();

#pragma unroll 2
    for (int t = 0; t < T_LEN; ++t) {
        const bool fl = ((t & 15) == 0) && (t > 0);

        // --- early LDS reads (A(t-1) fragments; I(t-1) lane-local scalars) ---
        f16x8 sA0 = ld_af(&Al[0][0], 0), sA1 = ld_af(&Al[0][0], 1);
        float Iv[4];
#pragma unroll
        for (int i = 0; i < 4; ++i) Iv[i] = (float)Il[4 * q + i][n];

        // flush-iter: issue next x-tile global loads early (drained once at alpha)
        float4 xla, xlb;
        if (fl) {
            int off = (t + 1) * 8 + xu * 8;
            if (off > T_LEN * 8 - 8) off = T_LEN * 8 - 8;
            xla = *(const float4*)(xgr + off);
            xlb = *(const float4*)(xgr + off + 4);
        }

        // --- MFMAs on resident regs (W,I terms), then A-terms when sA lands ---
        f32x4 w_a = MFMA(sW0, S1B[0], zero4); w_a = MFMA(sI0, S1B[2], w_a);
        f32x4 w_b = MFMA(sW1, S1B[1], zero4); w_b = MFMA(sI1, S1B[3], w_b);
        f32x4 g_a = MFMA(sI0, G1B[0], zero4), g_b = MFMA(sI1, G1B[1], zero4);
        f32x4 zp_a = MFMA(sI0, ZB[2], zero4), zp_c = MFMA(sI1, ZB[3], zero4);
        f32x4 rp_a = MFMA(sI0, RB[2], zero4), rp_c = MFMA(sI1, RB[3], zero4);

        w_a = MFMA(sA0, S1B[4], w_a);  w_b = MFMA(sA1, S1B[5], w_b);
        g_a = MFMA(sA0, G1B[2], g_a);  g_b = MFMA(sA1, G1B[3], g_b);
        zp_a = MFMA(sA0, ZB[4], zp_a); zp_c = MFMA(sA1, ZB[5], zp_c);
        rp_a = MFMA(sA0, RB[4], rp_a); rp_c = MFMA(sA1, RB[5], rp_c);
        f32x4 hp_a = MFMA(sA0, HB[4], zero4), hp_c = MFMA(sA1, HB[5], zero4);
        f32x4 ap_a = MFMA(sA0, AB[4], zero4), ap_c = MFMA(sA1, AB[5], zero4);

        // action(t-1) = A(t-1) @ phi (wave 0), buffered in LDS
        if (w == 0) {
            f32x4 act = MFMA(sA0, phiB[0], zero4);
            act = MFMA(sA1, phiB[1], act);
            if (t > 0 && c < O_DIM) {
                int sl = (t - 1) & 15;
#pragma unroll
                for (int i = 0; i < 4; ++i) actb[(4 * q + i) * 64 + sl * 4 + c] = act[i] + bias_p;
            }
        }

        // --- W_new ---
#pragma unroll
        for (int i = 0; i < 4; ++i) {
            float wn = tanh_f(xt[i] + w_a[i] + w_b[i]) * sigm_f(g_a[i] + g_b[i] + bias_g);
            Wl[4 * q + i][n] = (_Float16)wn;
        }
        __syncthreads();  // alpha: W_new visible (+ actb visible on flush iters)

        if (fl) {
            float* d = &xtile[xr * 132 + xu * 8];
            *(float4*)d = xla; *(float4*)(d + 4) = xlb;
            float4 av = *(const float4*)(&actb[xr * 64 + xu * 4]);
            *(float4*)(out + (size_t)(r0 + xr) * (T_LEN * O_DIM) + (t - 16 + xu) * 4) = av;
        }

        f16x8 nW0 = ld_af(&Wl[0][0], 0), nW1 = ld_af(&Wl[0][0], 1);
        zp_a = MFMA(nW0, ZB[0], zp_a); zp_c = MFMA(nW1, ZB[1], zp_c);
        rp_a = MFMA(nW0, RB[0], rp_a); rp_c = MFMA(nW1, RB[1], rp_c);
        hp_a = MFMA(nW0, HB[0], hp_a); hp_c = MFMA(nW1, HB[1], hp_c);
        ap_a = MFMA(nW0, AB[0], ap_a); ap_c = MFMA(nW1, AB[1], ap_c);
        f32x4 ag_a = MFMA(nW0, AGB[0], zero4), ag_c = MFMA(nW1, AGB[1], zero4);

        float zv[4];
#pragma unroll
        for (int i = 0; i < 4; ++i) {
            zv[i] = sigm_f(zp_a[i] + zp_c[i] + bias_z);
            float rv = sigm_f(rp_a[i] + rp_c[i] + bias_r);
            Rl[4 * q + i][n] = (_Float16)(rv * Iv[i]);
        }
        __syncthreads();  // beta: r*I visible (+ new x-tile visible)

        f16x8 hR0 = ld_af(&Rl[0][0], 0), hR1 = ld_af(&Rl[0][0], 1);

        // enc(t+1): state-independent, off the critical path
        float xtn[4];
        {
            const float* xs = &xtile[c * 132 + (t & 15) * 8];
            float4 qa = *(const float4*)xs;
            float4 qb = *(const float4*)(xs + 4);
            f16x8 xf;
            float m = (q == 0) ? 1.0f : 0.0f;
            xf[0] = (_Float16)(qa.x * m); xf[1] = (_Float16)(qa.y * m); xf[2] = (_Float16)(qa.z * m); xf[3] = (_Float16)(qa.w * m);
            xf[4] = (_Float16)(qb.x * m); xf[5] = (_Float16)(qb.y * m); xf[6] = (_Float16)(qb.z * m); xf[7] = (_Float16)(qb.w * m);
            f32x4 ep = MFMA(xf, encB, zero4);
#pragma unroll
            for (int i = 0; i < 4; ++i) xtn[i] = tanh_f(ep[i] + bias_e);
        }

        hp_a = MFMA(hR0, HB[2], hp_a); hp_c = MFMA(hR1, HB[3], hp_c);
#pragma unroll
        for (int i = 0; i < 4; ++i) {
            float hv = tanh_f(hp_a[i] + hp_c[i] + bias_h);
            float In = __builtin_fmaf(zv[i], hv - Iv[i], Iv[i]);
            Il[4 * q + i][n] = (_Float16)In;
        }
        __syncthreads();  // gamma: I_new visible

        f16x8 nI0 = ld_af(&Il[0][0], 0), nI1 = ld_af(&Il[0][0], 1);
        ap_a = MFMA(nI0, AB[2], ap_a); ap_c = MFMA(nI1, AB[3], ap_c);
        ag_a = MFMA(nI0, AGB[2], ag_a); ag_c = MFMA(nI1, AGB[3], ag_c);
#pragma unroll
        for (int i = 0; i < 4; ++i) {
            float av = tanh_f(ap_a[i] + ap_c[i]) * sigm_f(ag_a[i] + ag_c[i] + bias_ag);
            Al[4 * q + i][n] = (_Float16)av;
        }
        __syncthreads();  // delta: A_new visible

        sW0 = nW0; sW1 = nW1; sI0 = nI0; sI1 = nI1;
        xt[0] = xtn[0]; xt[1] = xtn[1]; xt[2] = xtn[2]; xt[3] = xtn[3];
    }

    // ---- epilogue: action(511) + final flush (acts 496..511) ----
    {
        f16x8 eA0 = ld_af(&Al[0][0], 0), eA1 = ld_af(&Al[0][0], 1);
        if (w == 0) {
            f32x4 act = MFMA(eA0, phiB[0], zero4);
            act = MFMA(eA1, phiB[1], act);
            if (c < O_DIM) {
#pragma unroll
                for (int i = 0; i < 4; ++i) actb[(4 * q + i) * 64 + 15 * 4 + c] = act[i] + bias_p;
            }
        }
        __syncthreads();
        float4 av = *(const float4*)(&actb[xr * 64 + xu * 4]);
        *(float4*)(out + (size_t)(r0 + xr) * (T_LEN * O_DIM) + (496 + xu) * 4) = av;
    }
}

extern "C" void kernel_launch(void* const* d_in, const int* in_sizes, int n_in,
                              void* d_out, int out_size, void* d_ws, size_t ws_size,
                              hipStream_t stream) {
    ANIMAZeroExact_86887188398421_kernel<<<dim3(64), dim3(256), 0, stream>>>(
        (const float*)d_in[0],
        (const float*)d_in[1],  (const float*)d_in[2],
        (const float*)d_in[3],  (const float*)d_in[4],  (const float*)d_in[5],
        (const float*)d_in[6],  (const float*)d_in[7],
        (const float*)d_in[8],  (const float*)d_in[9],
        (const float*)d_in[10], (const float*)d_in[11],
        (const float*)d_in[12], (const float*)d_in[13],
        (const float*)d_in[14], (const float*)d_in[15], (const float*)d_in[16],
        (const float*)d_in[17], (const float*)d_in[18],
        (const float*)d_in[19], (const float*)d_in[20],
        (float*)d_out);
}